// Round 28
// baseline (1103.595 us; speedup 1.0000x reference)
//
#include <hip/hip_runtime.h>

// AWQ dequant + GEMM, MI355X -- R28: SPLIT dequant-once (ws) + clean bf16 GEMM.
// Conventions (R26/R27 PASS): x fp32 [M,K]-C, q int32 [N,K]-C [0,16),
// s/z fp32 [G,N]-C, bias fp32 [N], out FP32 [M,N]-C.
// R27 post-mortem: VALU-bound on per-tile dequant (16x redundant per weight).
// R28: kernel1 dequantizes W->bf16 and converts x->bf16 ONCE into d_ws;
// kernel2 = R27 GEMM minus dequant (32KB bf16 staging/tile vs 160KB).
// Fallback to fused R27 path if ws_size < 107MB.

typedef __attribute__((ext_vector_type(8))) __bf16 bf16x8;
typedef __attribute__((ext_vector_type(4))) float f32x4;

#define BM 128
#define BN 128
#define BK 64
#define NTHREADS 256
#define NXCD 8

__device__ __forceinline__ unsigned short f_to_bf16(float f) {
  union { float f; unsigned int i; } c; c.f = f;
  unsigned int u = c.i;
  u += 0x7fffu + ((u >> 16) & 1u);   // RNE (finite)
  return (unsigned short)(u >> 16);
}

// ---------------- kernel 1: dequant W + convert x into workspace ----------
__global__ __launch_bounds__(256)
void dequant_kernel(const float* __restrict__ X, const int* __restrict__ Q,
                    const float* __restrict__ S, const float* __restrict__ Z,
                    unsigned short* __restrict__ Wb,   // [N,K] bf16
                    unsigned short* __restrict__ Xb,   // [M,K] bf16
                    int M, int N, int K, int GS)
{
  const size_t wcnt = (size_t)N * K / 8;   // 8 elems per thread
  const size_t xcnt = (size_t)M * K / 8;
  const size_t total = wcnt + xcnt;
  const size_t stride = (size_t)gridDim.x * 256;

  for (size_t idx = (size_t)blockIdx.x * 256 + threadIdx.x; idx < total; idx += stride) {
    if (idx < wcnt) {
      const int n  = (int)(idx / (K / 8));
      const int k0 = (int)(idx % (K / 8)) * 8;
      const int g  = k0 / GS;               // 8 elems same group (8 | 128)
      const float s = S[(size_t)g * N + n];
      const float z = Z[(size_t)g * N + n];
      const int4 q0 = *reinterpret_cast<const int4*>(Q + (size_t)n * K + k0);
      const int4 q1 = *reinterpret_cast<const int4*>(Q + (size_t)n * K + k0 + 4);
      ushort4 w0, w1;
      w0.x = f_to_bf16((float)q0.x * s + z); w0.y = f_to_bf16((float)q0.y * s + z);
      w0.z = f_to_bf16((float)q0.z * s + z); w0.w = f_to_bf16((float)q0.w * s + z);
      w1.x = f_to_bf16((float)q1.x * s + z); w1.y = f_to_bf16((float)q1.y * s + z);
      w1.z = f_to_bf16((float)q1.z * s + z); w1.w = f_to_bf16((float)q1.w * s + z);
      *reinterpret_cast<ushort4*>(Wb + (size_t)n * K + k0)     = w0;
      *reinterpret_cast<ushort4*>(Wb + (size_t)n * K + k0 + 4) = w1;
    } else {
      const size_t e0 = (idx - wcnt) * 8;
      const float4 v0 = *reinterpret_cast<const float4*>(X + e0);
      const float4 v1 = *reinterpret_cast<const float4*>(X + e0 + 4);
      ushort4 a0, a1;
      a0.x = f_to_bf16(v0.x); a0.y = f_to_bf16(v0.y);
      a0.z = f_to_bf16(v0.z); a0.w = f_to_bf16(v0.w);
      a1.x = f_to_bf16(v1.x); a1.y = f_to_bf16(v1.y);
      a1.z = f_to_bf16(v1.z); a1.w = f_to_bf16(v1.w);
      *reinterpret_cast<ushort4*>(Xb + e0)     = a0;
      *reinterpret_cast<ushort4*>(Xb + e0 + 4) = a1;
    }
  }
}

// ---------------- kernel 2: bf16 GEMM (B^T), swizzled LDS ----------------
__global__ __launch_bounds__(NTHREADS, 2)
void gemm_kernel(const unsigned short* __restrict__ Xb,
                 const unsigned short* __restrict__ Wb,
                 const float* __restrict__ Bias,
                 float* __restrict__ Out,
                 int M, int N, int K)
{
  __shared__ unsigned short As[BM * BK];
  __shared__ unsigned short Bs[BN * BK];

  const int tid  = threadIdx.x;
  const int wave = tid >> 6;
  const int lane = tid & 63;

  const int nwg = gridDim.x;
  int bid = blockIdx.x;
  if ((nwg % NXCD) == 0) {
    const int cpx = nwg / NXCD;
    bid = (blockIdx.x % NXCD) * cpx + blockIdx.x / NXCD;
  }
  const int mtiles = M / BM;
  const int mt = bid % mtiles;
  const int nt = bid / mtiles;
  const int m0 = mt * BM;
  const int n0 = nt * BN;

  const int wm = (wave >> 1) * 64;
  const int wn = (wave & 1) * 64;

  f32x4 acc[4][4];
#pragma unroll
  for (int i = 0; i < 4; ++i)
#pragma unroll
    for (int j = 0; j < 4; ++j)
      acc[i][j] = (f32x4){0.f, 0.f, 0.f, 0.f};

  const int ksteps = K / BK;
  for (int kt = 0; kt < ksteps; ++kt) {
    const int k0 = kt * BK;

    // ---- stage A+B tiles (bf16): 4 x 16B loads each, into regs
    int4 av[4], bv[4];
    const unsigned short* Ab = Xb + (size_t)m0 * K + k0;
    const unsigned short* Bb = Wb + (size_t)n0 * K + k0;
#pragma unroll
    for (int it = 0; it < 4; ++it) {
      const int elem = it * 2048 + tid * 8;          // 8192 ushorts per tile
      const int row = elem >> 6, col = elem & 63;
      av[it] = *reinterpret_cast<const int4*>(Ab + (size_t)row * K + col);
      bv[it] = *reinterpret_cast<const int4*>(Bb + (size_t)row * K + col);
    }

    __syncthreads();                       // prev tile consumed

#pragma unroll
    for (int it = 0; it < 4; ++it) {
      const int elem = it * 2048 + tid * 8;
      const int row = elem >> 6, col = elem & 63;
      const int sc = col ^ ((row & 7) << 3);         // T2 swizzle
      *reinterpret_cast<int4*>(&As[row * BK + sc]) = av[it];
      *reinterpret_cast<int4*>(&Bs[row * BK + sc]) = bv[it];
    }

    __syncthreads();                       // staging visible

    // ---- MFMA: 2 k-subtiles, 4x4 fragments, swizzled reads (0 conflicts)
#pragma unroll
    for (int kk = 0; kk < 2; ++kk) {
      const int klane = kk * 32 + (lane >> 4) * 8;
      bf16x8 a[4], b[4];
#pragma unroll
      for (int i = 0; i < 4; ++i) {
        const int row = wm + i * 16 + (lane & 15);
        a[i] = *reinterpret_cast<const bf16x8*>(
            &As[row * BK + (klane ^ ((row & 7) << 3))]);
      }
#pragma unroll
      for (int j = 0; j < 4; ++j) {
        const int row = wn + j * 16 + (lane & 15);
        b[j] = *reinterpret_cast<const bf16x8*>(
            &Bs[row * BK + (klane ^ ((row & 7) << 3))]);
      }
#pragma unroll
      for (int i = 0; i < 4; ++i)
#pragma unroll
        for (int j = 0; j < 4; ++j)
          acc[i][j] = __builtin_amdgcn_mfma_f32_16x16x32_bf16(a[i], b[j], acc[i][j], 0, 0, 0);
    }
  }

  // ---- Epilogue (C/D map m89/m91): col=lane&15, row=(lane>>4)*4+r
  const int colbase = n0 + wn + (lane & 15);
  const int rowbase = m0 + wm + ((lane >> 4) << 2);
#pragma unroll
  for (int j = 0; j < 4; ++j) {
    const int col = colbase + j * 16;
    const float bvv = Bias[col];
#pragma unroll
    for (int i = 0; i < 4; ++i) {
      const int row = rowbase + i * 16;
#pragma unroll
      for (int r = 0; r < 4; ++r)
        Out[(size_t)(row + r) * N + col] = acc[i][j][r] + bvv;
    }
  }
}

// ---------------- fallback: R27 fused kernel (ws too small) ----------------
__global__ __launch_bounds__(NTHREADS, 2)
void fused_kernel(const float* __restrict__ X, const int* __restrict__ Q,
                  const float* __restrict__ S, const float* __restrict__ Z,
                  const float* __restrict__ Bias, float* __restrict__ Out,
                  int M, int N, int K, int GS)
{
  __shared__ unsigned short As[BM * BK];
  __shared__ unsigned short Bs[BN * BK];
  const int tid = threadIdx.x, wave = tid >> 6, lane = tid & 63;
  const int nwg = gridDim.x;
  int bid = blockIdx.x;
  if ((nwg % NXCD) == 0) {
    const int cpx = nwg / NXCD;
    bid = (blockIdx.x % NXCD) * cpx + blockIdx.x / NXCD;
  }
  const int mtiles = M / BM;
  const int mt = bid % mtiles, nt = bid / mtiles;
  const int m0 = mt * BM, n0 = nt * BN;
  const int wm = (wave >> 1) * 64, wn = (wave & 1) * 64;
  f32x4 acc[4][4];
#pragma unroll
  for (int i = 0; i < 4; ++i)
#pragma unroll
    for (int j = 0; j < 4; ++j) acc[i][j] = (f32x4){0.f, 0.f, 0.f, 0.f};
  const int bn_row = tid >> 4, bk_col = (tid & 15) * 4;
  const int ksteps = K / BK;
  int4 qv[8]; float sf[8], zf[8];
#pragma unroll
  for (int it = 0; it < 8; ++it) {
    const int n = it * 16 + bn_row;
    qv[it] = *reinterpret_cast<const int4*>(Q + (size_t)(n0 + n) * K + bk_col);
    sf[it] = S[(size_t)(n0 + n)]; zf[it] = Z[(size_t)(n0 + n)];
  }
  for (int kt = 0; kt < ksteps; ++kt) {
    const int k0 = kt * BK;
    __syncthreads();
    const float* Xf = X + (size_t)m0 * K + k0;
    float4 av[8];
#pragma unroll
    for (int it = 0; it < 8; ++it) {
      const int elem = it * 1024 + tid * 4;
      av[it] = *reinterpret_cast<const float4*>(Xf + (size_t)(elem >> 6) * K + (elem & 63));
    }
#pragma unroll
    for (int it = 0; it < 8; ++it) {
      const int n = it * 16 + bn_row;
      ushort4 w;
      w.x = f_to_bf16((float)qv[it].x * sf[it] + zf[it]);
      w.y = f_to_bf16((float)qv[it].y * sf[it] + zf[it]);
      w.z = f_to_bf16((float)qv[it].z * sf[it] + zf[it]);
      w.w = f_to_bf16((float)qv[it].w * sf[it] + zf[it]);
      *reinterpret_cast<ushort4*>(&Bs[n * BK + (bk_col ^ ((n & 7) << 3))]) = w;
    }
#pragma unroll
    for (int it = 0; it < 8; ++it) {
      const int elem = it * 1024 + tid * 4;
      const int row = elem >> 6, col = elem & 63;
      ushort4 w;
      w.x = f_to_bf16(av[it].x); w.y = f_to_bf16(av[it].y);
      w.z = f_to_bf16(av[it].z); w.w = f_to_bf16(av[it].w);
      *reinterpret_cast<ushort4*>(&As[row * BK + (col ^ ((row & 7) << 3))]) = w;
    }
    __syncthreads();
    if (kt + 1 < ksteps) {
      const int k0n = k0 + BK, gn = k0n / GS;
#pragma unroll
      for (int it = 0; it < 8; ++it) {
        const int n = it * 16 + bn_row;
        qv[it] = *reinterpret_cast<const int4*>(Q + (size_t)(n0 + n) * K + k0n + bk_col);
        sf[it] = S[(size_t)gn * N + n0 + n]; zf[it] = Z[(size_t)gn * N + n0 + n];
      }
    }
#pragma unroll
    for (int kk = 0; kk < 2; ++kk) {
      const int klane = kk * 32 + (lane >> 4) * 8;
      bf16x8 a[4], b[4];
#pragma unroll
      for (int i = 0; i < 4; ++i) {
        const int row = wm + i * 16 + (lane & 15);
        a[i] = *reinterpret_cast<const bf16x8*>(&As[row * BK + (klane ^ ((row & 7) << 3))]);
      }
#pragma unroll
      for (int j = 0; j < 4; ++j) {
        const int row = wn + j * 16 + (lane & 15);
        b[j] = *reinterpret_cast<const bf16x8*>(&Bs[row * BK + (klane ^ ((row & 7) << 3))]);
      }
#pragma unroll
      for (int i = 0; i < 4; ++i)
#pragma unroll
        for (int j = 0; j < 4; ++j)
          acc[i][j] = __builtin_amdgcn_mfma_f32_16x16x32_bf16(a[i], b[j], acc[i][j], 0, 0, 0);
    }
  }
  const int colbase = n0 + wn + (lane & 15);
  const int rowbase = m0 + wm + ((lane >> 4) << 2);
#pragma unroll
  for (int j = 0; j < 4; ++j) {
    const int col = colbase + j * 16;
    const float bv = Bias[col];
#pragma unroll
    for (int i = 0; i < 4; ++i) {
      const int row = rowbase + i * 16;
#pragma unroll
      for (int r = 0; r < 4; ++r)
        Out[(size_t)(row + r) * N + col] = acc[i][j][r] + bv;
    }
  }
}

extern "C" void kernel_launch(void* const* d_in, const int* in_sizes, int n_in,
                              void* d_out, int out_size, void* d_ws, size_t ws_size,
                              hipStream_t stream) {
  const float* x    = (const float*)d_in[0];
  const int*   q    = (const int*)d_in[1];
  const float* s    = (const float*)d_in[2];
  const float* z    = (const float*)d_in[3];
  const float* bias = (const float*)d_in[4];
  float*       out  = (float*)d_out;

  const int N  = in_sizes[4];              // 11008
  const int K  = in_sizes[1] / N;          // 4096
  const int M  = in_sizes[0] / K;          // 2048
  const int G  = in_sizes[2] / N;          // 32
  const int GS = K / G;                    // 128

  const size_t need = ((size_t)N * K + (size_t)M * K) * sizeof(unsigned short);
  const int grid = (M / BM) * (N / BN);    // 1376

  if (ws_size >= need) {
    unsigned short* Wb = (unsigned short*)d_ws;           // [N,K]
    unsigned short* Xb = Wb + (size_t)N * K;              // [M,K]
    dequant_kernel<<<2048, 256, 0, stream>>>(x, q, s, z, Wb, Xb, M, N, K, GS);
    gemm_kernel<<<grid, NTHREADS, 0, stream>>>(Xb, Wb, bias, out, M, N, K);
  } else {
    fused_kernel<<<grid, NTHREADS, 0, stream>>>(x, q, s, z, bias, out, M, N, K, GS);
  }
}

// Round 29
// 458.114 us; speedup vs baseline: 2.4090x; 2.4090x over previous
//
#include <hip/hip_runtime.h>
#include <hip/hip_bf16.h>

// AWQ fused dequant + GEMM, MI355X -- R29.
// Conventions (R26/R27 PASS): x fp32 [M,K]-C, q int32 [N,K]-C [0,16),
// s/z fp32 [G,N]-C, bias fp32 [N], out FP32 [M,N]-C.
// R28 post-mortem: split-kernel spilled (VGPR 64, 2.3GB scratch writes) ->
// reverted to R27 skeleton. R29 surgical changes:
//  - native v_cvt_pk_bf16_f32 via __float22bfloat162_rn (1 op / 2 elems)
//    replaces 5-op manual RNE (A: 160->16 ops, B pack: 96->8 ops per thread)
//  - BM 256 (512 thr, 8 waves, 48KB LDS): halves B-dequant redundancy
//  - A and B both reg-prefetched across the MFMA phase
// Expected: VALU ~160cyc ~ MFMA 155cyc per wave per K-step (balanced).

typedef __attribute__((ext_vector_type(8))) __bf16 bf16x8;
typedef __attribute__((ext_vector_type(4))) float f32x4;

#define BM 256
#define BN 128
#define BK 64
#define NTHREADS 512
#define NXCD 8

__device__ __forceinline__ unsigned int pk_bf16(float lo, float hi) {
  __hip_bfloat162 h = __float22bfloat162_rn(float2{lo, hi});  // v_cvt_pk_bf16_f32, RNE
  union { __hip_bfloat162 h; unsigned int u; } c; c.h = h;
  return c.u;   // low 16 = lo, high 16 = hi
}

__global__ __launch_bounds__(NTHREADS, 2)
void awq_gemm_kernel(const float* __restrict__ X,
                     const int* __restrict__ Q,
                     const float* __restrict__ S,
                     const float* __restrict__ Z,
                     const float* __restrict__ Bias,
                     float* __restrict__ Out,
                     int M, int N, int K, int GS)
{
  __shared__ unsigned short As[BM * BK];   // 32 KiB x tile bf16, XOR-swizzled
  __shared__ unsigned short Bs[BN * BK];   // 16 KiB weight tile bf16, XOR-swizzled

  const int tid  = threadIdx.x;
  const int wave = tid >> 6;               // 0..7
  const int lane = tid & 63;

  // T1: bijective XCD chunk swizzle (grid 688 = 8*86)
  const int nwg = gridDim.x;
  int bid = blockIdx.x;
  if ((nwg % NXCD) == 0) {
    const int cpx = nwg / NXCD;
    bid = (blockIdx.x % NXCD) * cpx + blockIdx.x / NXCD;
  }
  const int mtiles = M / BM;               // 8
  const int mt = bid % mtiles;             // mt fastest -> q-panel L2 reuse
  const int nt = bid / mtiles;
  const int m0 = mt * BM;
  const int n0 = nt * BN;

  // 4x2 wave grid, each wave owns 64x64 of the 256x128 tile
  const int wm = (wave >> 1) * 64;
  const int wn = (wave & 1) * 64;

  f32x4 acc[4][4];
#pragma unroll
  for (int i = 0; i < 4; ++i)
#pragma unroll
    for (int j = 0; j < 4; ++j)
      acc[i][j] = (f32x4){0.f, 0.f, 0.f, 0.f};

  // B staging map: thread -> (n-row, 16 k-cols)
  const int bn  = tid >> 2;                // 0..127
  const int bkc = (tid & 3) * 16;          // 0,16,32,48

  const int ksteps = K / BK;

  // ---- prologue: prefetch A,B,s,z for kt=0
  float4 av[8];
  int4   qv[4];
  float  sf, zf;
  {
    const float* Xf = X + (size_t)m0 * K;
#pragma unroll
    for (int it = 0; it < 8; ++it) {
      const int elem = it * 2048 + tid * 4;          // 16384 elems
      av[it] = *reinterpret_cast<const float4*>(
          Xf + (size_t)(elem >> 6) * K + (elem & 63));
    }
    const int* Qp = Q + (size_t)(n0 + bn) * K + bkc;
#pragma unroll
    for (int j = 0; j < 4; ++j)
      qv[j] = *reinterpret_cast<const int4*>(Qp + j * 4);
    sf = S[(size_t)0 * N + n0 + bn];
    zf = Z[(size_t)0 * N + n0 + bn];
  }

  for (int kt = 0; kt < ksteps; ++kt) {
    __syncthreads();                       // prev tile fully consumed

    // ---- B: dequant from prefetched regs -> swizzled LDS (16 elems/thread)
    {
      unsigned int w[8];
#pragma unroll
      for (int j = 0; j < 4; ++j) {
        const float f0 = (float)qv[j].x * sf + zf;
        const float f1 = (float)qv[j].y * sf + zf;
        const float f2 = (float)qv[j].z * sf + zf;
        const float f3 = (float)qv[j].w * sf + zf;
        w[j * 2]     = pk_bf16(f0, f1);
        w[j * 2 + 1] = pk_bf16(f2, f3);
      }
      const int swz = (bn & 7) << 3;
      const int c0 = bkc ^ swz, c1 = (bkc + 8) ^ swz;
      *reinterpret_cast<int4*>(&Bs[bn * BK + c0]) =
          make_int4(w[0], w[1], w[2], w[3]);
      *reinterpret_cast<int4*>(&Bs[bn * BK + c1]) =
          make_int4(w[4], w[5], w[6], w[7]);
    }

    // ---- A: cvt_pk from prefetched regs -> swizzled LDS (32 elems/thread)
#pragma unroll
    for (int it = 0; it < 8; ++it) {
      const int elem = it * 2048 + tid * 4;
      const int row = elem >> 6, col = elem & 63;
      const unsigned int u0 = pk_bf16(av[it].x, av[it].y);
      const unsigned int u1 = pk_bf16(av[it].z, av[it].w);
      *reinterpret_cast<uint2*>(
          &As[row * BK + (col ^ ((row & 7) << 3))]) = make_uint2(u0, u1);
    }

    __syncthreads();                       // staging visible

    // ---- prefetch A,B,s,z for kt+1 (completes under MFMA)
    if (kt + 1 < ksteps) {
      const int k0n = (kt + 1) * BK;
      const int gn  = k0n / GS;
      const float* Xf = X + (size_t)m0 * K + k0n;
#pragma unroll
      for (int it = 0; it < 8; ++it) {
        const int elem = it * 2048 + tid * 4;
        av[it] = *reinterpret_cast<const float4*>(
            Xf + (size_t)(elem >> 6) * K + (elem & 63));
      }
      const int* Qp = Q + (size_t)(n0 + bn) * K + k0n + bkc;
#pragma unroll
      for (int j = 0; j < 4; ++j)
        qv[j] = *reinterpret_cast<const int4*>(Qp + j * 4);
      sf = S[(size_t)gn * N + n0 + bn];
      zf = Z[(size_t)gn * N + n0 + bn];
    }

    // ---- MFMA: 2 k-subtiles, 4x4 fragments, swizzled reads (0 conflicts)
#pragma unroll
    for (int kk = 0; kk < 2; ++kk) {
      const int klane = kk * 32 + (lane >> 4) * 8;
      bf16x8 a[4], b[4];
#pragma unroll
      for (int i = 0; i < 4; ++i) {
        const int row = wm + i * 16 + (lane & 15);
        a[i] = *reinterpret_cast<const bf16x8*>(
            &As[row * BK + (klane ^ ((row & 7) << 3))]);
      }
#pragma unroll
      for (int j = 0; j < 4; ++j) {
        const int row = wn + j * 16 + (lane & 15);
        b[j] = *reinterpret_cast<const bf16x8*>(
            &Bs[row * BK + (klane ^ ((row & 7) << 3))]);
      }
#pragma unroll
      for (int i = 0; i < 4; ++i)
#pragma unroll
        for (int j = 0; j < 4; ++j)
          acc[i][j] = __builtin_amdgcn_mfma_f32_16x16x32_bf16(a[i], b[j], acc[i][j], 0, 0, 0);
    }
  }

  // ---- Epilogue (C/D map m89/m91): col=lane&15, row=(lane>>4)*4+r
  const int colbase = n0 + wn + (lane & 15);
  const int rowbase = m0 + wm + ((lane >> 4) << 2);
#pragma unroll
  for (int j = 0; j < 4; ++j) {
    const int col = colbase + j * 16;
    const float bv = Bias[col];
#pragma unroll
    for (int i = 0; i < 4; ++i) {
      const int row = rowbase + i * 16;
#pragma unroll
      for (int r = 0; r < 4; ++r)
        Out[(size_t)(row + r) * N + col] = acc[i][j][r] + bv;
    }
  }
}

extern "C" void kernel_launch(void* const* d_in, const int* in_sizes, int n_in,
                              void* d_out, int out_size, void* d_ws, size_t ws_size,
                              hipStream_t stream) {
  const float* x    = (const float*)d_in[0];
  const int*   q    = (const int*)d_in[1];
  const float* s    = (const float*)d_in[2];
  const float* z    = (const float*)d_in[3];
  const float* bias = (const float*)d_in[4];
  float*       out  = (float*)d_out;

  const int N  = in_sizes[4];              // 11008
  const int K  = in_sizes[1] / N;          // 4096
  const int M  = in_sizes[0] / K;          // 2048
  const int G  = in_sizes[2] / N;          // 32
  const int GS = K / G;                    // 128

  const int grid = (M / BM) * (N / BN);    // 8 * 86 = 688
  awq_gemm_kernel<<<grid, NTHREADS, 0, stream>>>(x, q, s, z, bias, out, M, N, K, GS);
}

// Round 30
// 373.194 us; speedup vs baseline: 2.9572x; 1.2275x over previous
//
#include <hip/hip_runtime.h>
#include <hip/hip_bf16.h>

// AWQ fused dequant + GEMM, MI355X -- R30.
// Conventions (R26+ PASS): x fp32 [M,K]-C, q int32 [N,K]-C [0,16),
// s/z fp32 [G,N]-C, bias fp32 [N], out FP32 [M,N]-C.
// R29 post-mortem: not VALU-bound (VALU total ~20us vs MFMA floor ~89us);
// 5x stall overhead from barrier drains with too few co-resident blocks.
// R30: back to 128^2/256thr (R27 codegen, ~5 blocks/CU) + A-operand staged
// by global_load_lds DMA from a PRE-CONVERTED, PRE-SWIZZLED bf16 copy of x
// in d_ws (m97 lever; rule#21: linear DMA dest + swizzled source + swizzled
// read). B stays fused dequant with v_cvt_pk_bf16_f32.

typedef __attribute__((ext_vector_type(8))) __bf16 bf16x8;
typedef __attribute__((ext_vector_type(4))) float f32x4;

#define BM 128
#define BN 128
#define BK 64
#define NTHREADS 256
#define NXCD 8

__device__ __forceinline__ unsigned int pk_bf16(float lo, float hi) {
  __hip_bfloat162 h = __float22bfloat162_rn(float2{lo, hi});  // v_cvt_pk_bf16_f32
  union { __hip_bfloat162 h; unsigned int u; } c; c.h = h;
  return c.u;
}

__device__ __forceinline__ void gload_lds16(const void* g, void* lds) {
  __builtin_amdgcn_global_load_lds(
      (const __attribute__((address_space(1))) unsigned int*)g,
      (__attribute__((address_space(3))) unsigned int*)lds, 16, 0, 0);
}

// ---- kernel1: x fp32 [M,K] -> Xb bf16, tile-blob layout with T2 pre-swizzle.
// Blob t = mt*(K/64)+kt holds tile (mt,kt): ushort at t*8192 + row*64 + (col^((row&7)<<3)).
__global__ __launch_bounds__(256)
void xconv_kernel(const float* __restrict__ X, unsigned short* __restrict__ Xb,
                  int M, int K)
{
  const unsigned int idx = blockIdx.x * 256 + threadIdx.x;   // 8 elems/thread
  const unsigned int e = idx * 8;
  if (e >= (unsigned int)(M * K)) return;
  const unsigned int m = e / (unsigned int)K;
  const unsigned int k = e % (unsigned int)K;
  const unsigned int mt = m >> 7, row = m & 127;
  const unsigned int kt = k >> 6, col = k & 63;              // col multiple of 8
  const unsigned int swz = (row & 7) << 3;
  const unsigned int dst = (mt * (K >> 6) + kt) * 8192u + row * 64u + (col ^ swz);

  const float4 v0 = *reinterpret_cast<const float4*>(X + e);
  const float4 v1 = *reinterpret_cast<const float4*>(X + e + 4);
  const unsigned int u0 = pk_bf16(v0.x, v0.y);
  const unsigned int u1 = pk_bf16(v0.z, v0.w);
  const unsigned int u2 = pk_bf16(v1.x, v1.y);
  const unsigned int u3 = pk_bf16(v1.z, v1.w);
  *reinterpret_cast<uint4*>(Xb + dst) = make_uint4(u0, u1, u2, u3);
}

// ---- kernel2: GEMM. A via global_load_lds DMA; B fused dequant (cvt_pk).
__global__ __launch_bounds__(NTHREADS, 2)
void awq_gemm_kernel(const unsigned short* __restrict__ Xb,
                     const int* __restrict__ Q,
                     const float* __restrict__ S,
                     const float* __restrict__ Z,
                     const float* __restrict__ Bias,
                     float* __restrict__ Out,
                     int M, int N, int K, int GS)
{
  __shared__ unsigned short As[BM * BK];   // filled by DMA (pre-swizzled blob)
  __shared__ unsigned short Bs[BN * BK];   // fused-dequant bf16, XOR-swizzled

  const int tid  = threadIdx.x;
  const int wave = tid >> 6;
  const int lane = tid & 63;

  const int nwg = gridDim.x;
  int bid = blockIdx.x;
  if ((nwg % NXCD) == 0) {
    const int cpx = nwg / NXCD;
    bid = (blockIdx.x % NXCD) * cpx + blockIdx.x / NXCD;
  }
  const int mtiles = M / BM;
  const int mt = bid % mtiles;             // mt fastest -> q-panel L2 reuse
  const int nt = bid / mtiles;
  const int m0 = mt * BM;
  const int n0 = nt * BN;

  const int wm = (wave >> 1) * 64;         // 2x2 wave grid
  const int wn = (wave & 1) * 64;

  f32x4 acc[4][4];
#pragma unroll
  for (int i = 0; i < 4; ++i)
#pragma unroll
    for (int j = 0; j < 4; ++j)
      acc[i][j] = (f32x4){0.f, 0.f, 0.f, 0.f};

  const int bn_row = tid >> 4;             // 0..15
  const int bk_col = (tid & 15) * 4;       // 0..60
  const int ktiles = K / BK;

  // A blob base for this block's m-tile row
  const unsigned short* Ablob = Xb + (size_t)mt * ktiles * (BM * BK);

  // ---- prologue: prefetch q/s/z for kt=0
  int4  qv[8];
  float sf[8], zf[8];
#pragma unroll
  for (int it = 0; it < 8; ++it) {
    const int n = it * 16 + bn_row;
    qv[it] = *reinterpret_cast<const int4*>(Q + (size_t)(n0 + n) * K + bk_col);
    sf[it] = S[(size_t)0 * N + n0 + n];
    zf[it] = Z[(size_t)0 * N + n0 + n];
  }

  for (int kt = 0; kt < ktiles; ++kt) {
    __syncthreads();                       // prev tile fully consumed

    // ---- A: 16KB blob -> LDS via DMA (4 issues/wave, 1KB each, linear)
    {
      const unsigned short* src = Ablob + (size_t)kt * (BM * BK);
#pragma unroll
      for (int it = 0; it < 4; ++it) {
        const int chunk = wave * 4 + it;   // 16 x 1KB chunks
        gload_lds16(src + chunk * 512 + lane * 8, (char*)As + chunk * 1024);
      }
    }

    // ---- B: dequant prefetched regs -> swizzled LDS (32 elems/thread)
#pragma unroll
    for (int it = 0; it < 8; ++it) {
      const int n = it * 16 + bn_row;
      const unsigned int w0 = pk_bf16((float)qv[it].x * sf[it] + zf[it],
                                      (float)qv[it].y * sf[it] + zf[it]);
      const unsigned int w1 = pk_bf16((float)qv[it].z * sf[it] + zf[it],
                                      (float)qv[it].w * sf[it] + zf[it]);
      *reinterpret_cast<uint2*>(
          &Bs[n * BK + (bk_col ^ ((n & 7) << 3))]) = make_uint2(w0, w1);
    }

    __syncthreads();                       // DMA drained (compiler vmcnt) + B visible

    // ---- prefetch q/s/z for kt+1 (completes under MFMA)
    if (kt + 1 < ktiles) {
      const int k0n = (kt + 1) * BK;
      const int gn  = k0n / GS;
#pragma unroll
      for (int it = 0; it < 8; ++it) {
        const int n = it * 16 + bn_row;
        qv[it] = *reinterpret_cast<const int4*>(
            Q + (size_t)(n0 + n) * K + k0n + bk_col);
        sf[it] = S[(size_t)gn * N + n0 + n];
        zf[it] = Z[(size_t)gn * N + n0 + n];
      }
    }

    // ---- MFMA: 2 k-subtiles, 4x4 fragments, swizzled reads (0 conflicts)
#pragma unroll
    for (int kk = 0; kk < 2; ++kk) {
      const int klane = kk * 32 + (lane >> 4) * 8;
      bf16x8 a[4], b[4];
#pragma unroll
      for (int i = 0; i < 4; ++i) {
        const int row = wm + i * 16 + (lane & 15);
        a[i] = *reinterpret_cast<const bf16x8*>(
            &As[row * BK + (klane ^ ((row & 7) << 3))]);
      }
#pragma unroll
      for (int j = 0; j < 4; ++j) {
        const int row = wn + j * 16 + (lane & 15);
        b[j] = *reinterpret_cast<const bf16x8*>(
            &Bs[row * BK + (klane ^ ((row & 7) << 3))]);
      }
#pragma unroll
      for (int i = 0; i < 4; ++i)
#pragma unroll
        for (int j = 0; j < 4; ++j)
          acc[i][j] = __builtin_amdgcn_mfma_f32_16x16x32_bf16(a[i], b[j], acc[i][j], 0, 0, 0);
    }
  }

  // ---- Epilogue (C/D map m89/m91): col=lane&15, row=(lane>>4)*4+r
  const int colbase = n0 + wn + (lane & 15);
  const int rowbase = m0 + wm + ((lane >> 4) << 2);
#pragma unroll
  for (int j = 0; j < 4; ++j) {
    const int col = colbase + j * 16;
    const float bv = Bias[col];
#pragma unroll
    for (int i = 0; i < 4; ++i) {
      const int row = rowbase + i * 16;
#pragma unroll
      for (int r = 0; r < 4; ++r)
        Out[(size_t)(row + r) * N + col] = acc[i][j][r] + bv;
    }
  }
}

extern "C" void kernel_launch(void* const* d_in, const int* in_sizes, int n_in,
                              void* d_out, int out_size, void* d_ws, size_t ws_size,
                              hipStream_t stream) {
  const float* x    = (const float*)d_in[0];
  const int*   q    = (const int*)d_in[1];
  const float* s    = (const float*)d_in[2];
  const float* z    = (const float*)d_in[3];
  const float* bias = (const float*)d_in[4];
  float*       out  = (float*)d_out;

  const int N  = in_sizes[4];              // 11008
  const int K  = in_sizes[1] / N;          // 4096
  const int M  = in_sizes[0] / K;          // 2048
  const int G  = in_sizes[2] / N;          // 32
  const int GS = K / G;                    // 128

  unsigned short* Xb = (unsigned short*)d_ws;   // M*K*2 = 16.8MB (ws >= 107MB, R28-proven)

  const int cblocks = (M * K / 8 + 255) / 256;  // 4096
  xconv_kernel<<<cblocks, 256, 0, stream>>>(x, Xb, M, K);

  const int grid = (M / BM) * (N / BN);         // 1376 = 8*172
  awq_gemm_kernel<<<grid, NTHREADS, 0, stream>>>(Xb, q, s, z, bias, out, M, N, K, GS);
}

// Round 31
// 256.827 us; speedup vs baseline: 4.2970x; 1.4531x over previous
//
#include <hip/hip_runtime.h>
#include <hip/hip_bf16.h>

// AWQ dequant + GEMM, MI355X -- R31: dequant-once + PURE DUAL-DMA GEMM (m97).
// Conventions (R26+ PASS): x fp32 [M,K]-C, q int32 [N,K]-C [0,16),
// s/z fp32 [G,N]-C, bias fp32 [N], out FP32 [M,N]-C.
// R30 post-mortem: B-staging (q loads + dequant VALU) between the barriers
// keeps us at 458 TF; m97 proves this skeleton does 874-912 TF when BOTH
// operands arrive via global_load_lds with nothing else in the K-step.
// R31: pre-pass dequantizes W->bf16 blobs (pre-swizzled, rule#21) into d_ws
// next to the Xb blobs; GEMM K-step = 8 DMA issues + 2 barriers + 32 MFMA.
// ws need = (N*K + M*K)*2 = 107MB (<= ws_size, R28-verified).

typedef __attribute__((ext_vector_type(8))) __bf16 bf16x8;
typedef __attribute__((ext_vector_type(4))) float f32x4;

#define BM 128
#define BN 128
#define BK 64
#define NTHREADS 256
#define NXCD 8

__device__ __forceinline__ unsigned int pk_bf16(float lo, float hi) {
  __hip_bfloat162 h = __float22bfloat162_rn(float2{lo, hi});  // v_cvt_pk_bf16_f32
  union { __hip_bfloat162 h; unsigned int u; } c; c.h = h;
  return c.u;
}

__device__ __forceinline__ void gload_lds16(const void* g, void* lds) {
  __builtin_amdgcn_global_load_lds(
      (const __attribute__((address_space(1))) unsigned int*)g,
      (__attribute__((address_space(3))) unsigned int*)lds, 16, 0, 0);
}

// ---- pre-pass 1: q int32 [N,K] -> Wb bf16 tile-blobs, T2 pre-swizzled.
// Blob t = ntile*(K/64)+kt holds tile rows n=ntile*128.., cols k=kt*64..:
//   ushort at t*8192 + row*64 + (col ^ ((row&7)<<3)), row=n&127, col=k&63.
__global__ __launch_bounds__(256)
void wdequant_kernel(const int* __restrict__ Q,
                     const float* __restrict__ S, const float* __restrict__ Z,
                     unsigned short* __restrict__ Wb, int N, int K, int GS)
{
  const unsigned int idx = blockIdx.x * 256 + threadIdx.x;   // 8 elems/thread
  const unsigned long long e = (unsigned long long)idx * 8;
  if (e >= (unsigned long long)N * K) return;
  const unsigned int n = (unsigned int)(e / (unsigned int)K);
  const unsigned int k = (unsigned int)(e % (unsigned int)K);
  const unsigned int g = k / (unsigned int)GS;                // 8 | GS
  const float s = S[(size_t)g * N + n];
  const float z = Z[(size_t)g * N + n];
  const int4 q0 = *reinterpret_cast<const int4*>(Q + e);
  const int4 q1 = *reinterpret_cast<const int4*>(Q + e + 4);
  const unsigned int u0 = pk_bf16((float)q0.x * s + z, (float)q0.y * s + z);
  const unsigned int u1 = pk_bf16((float)q0.z * s + z, (float)q0.w * s + z);
  const unsigned int u2 = pk_bf16((float)q1.x * s + z, (float)q1.y * s + z);
  const unsigned int u3 = pk_bf16((float)q1.z * s + z, (float)q1.w * s + z);

  const unsigned int ntile = n >> 7, row = n & 127;
  const unsigned int kt = k >> 6, col = k & 63;               // col mult of 8
  const unsigned int dst = (ntile * (K >> 6) + kt) * 8192u + row * 64u
                         + (col ^ ((row & 7) << 3));
  *reinterpret_cast<uint4*>(Wb + dst) = make_uint4(u0, u1, u2, u3);
}

// ---- pre-pass 2: x fp32 [M,K] -> Xb bf16 tile-blobs, T2 pre-swizzled.
__global__ __launch_bounds__(256)
void xconv_kernel(const float* __restrict__ X, unsigned short* __restrict__ Xb,
                  int M, int K)
{
  const unsigned int idx = blockIdx.x * 256 + threadIdx.x;
  const unsigned int e = idx * 8;
  if (e >= (unsigned int)(M * K)) return;
  const unsigned int m = e / (unsigned int)K;
  const unsigned int k = e % (unsigned int)K;
  const unsigned int mt = m >> 7, row = m & 127;
  const unsigned int kt = k >> 6, col = k & 63;
  const unsigned int dst = (mt * (K >> 6) + kt) * 8192u + row * 64u
                         + (col ^ ((row & 7) << 3));
  const float4 v0 = *reinterpret_cast<const float4*>(X + e);
  const float4 v1 = *reinterpret_cast<const float4*>(X + e + 4);
  *reinterpret_cast<uint4*>(Xb + dst) =
      make_uint4(pk_bf16(v0.x, v0.y), pk_bf16(v0.z, v0.w),
                 pk_bf16(v1.x, v1.y), pk_bf16(v1.z, v1.w));
}

// ---- GEMM: both operands via global_load_lds (m97 structure).
__global__ __launch_bounds__(NTHREADS, 2)
void gemm_kernel(const unsigned short* __restrict__ Xb,
                 const unsigned short* __restrict__ Wb,
                 const float* __restrict__ Bias,
                 float* __restrict__ Out, int M, int N, int K)
{
  __shared__ unsigned short As[BM * BK];   // DMA-filled, pre-swizzled
  __shared__ unsigned short Bs[BN * BK];   // DMA-filled, pre-swizzled

  const int tid  = threadIdx.x;
  const int wave = tid >> 6;
  const int lane = tid & 63;

  const int nwg = gridDim.x;
  int bid = blockIdx.x;
  if ((nwg % NXCD) == 0) {
    const int cpx = nwg / NXCD;
    bid = (blockIdx.x % NXCD) * cpx + blockIdx.x / NXCD;
  }
  const int mtiles = M / BM;
  const int mt = bid % mtiles;             // mt fastest -> W-panel L2 reuse
  const int nt = bid / mtiles;
  const int m0 = mt * BM;
  const int n0 = nt * BN;

  const int wm = (wave >> 1) * 64;         // 2x2 wave grid
  const int wn = (wave & 1) * 64;

  f32x4 acc[4][4];
#pragma unroll
  for (int i = 0; i < 4; ++i)
#pragma unroll
    for (int j = 0; j < 4; ++j)
      acc[i][j] = (f32x4){0.f, 0.f, 0.f, 0.f};

  const int ktiles = K / BK;
  const unsigned short* Ablob = Xb + (size_t)mt * ktiles * (BM * BK);
  const unsigned short* Bblob = Wb + (size_t)nt * ktiles * (BN * BK);

  for (int kt = 0; kt < ktiles; ++kt) {
    __syncthreads();                       // prev tile consumed

    // ---- 8 DMA issues/wave: A chunks + B chunks (1KB each, linear dest)
    {
      const unsigned short* asrc = Ablob + (size_t)kt * (BM * BK);
      const unsigned short* bsrc = Bblob + (size_t)kt * (BN * BK);
#pragma unroll
      for (int it = 0; it < 4; ++it) {
        const int chunk = wave * 4 + it;   // 16 x 1KB per tile
        gload_lds16(asrc + chunk * 512 + lane * 8, (char*)As + chunk * 1024);
        gload_lds16(bsrc + chunk * 512 + lane * 8, (char*)Bs + chunk * 1024);
      }
    }

    __syncthreads();                       // DMA drained (compiler vmcnt(0))

    // ---- MFMA: 2 k-subtiles, 4x4 fragments, swizzled reads (0 conflicts)
#pragma unroll
    for (int kk = 0; kk < 2; ++kk) {
      const int klane = kk * 32 + (lane >> 4) * 8;
      bf16x8 a[4], b[4];
#pragma unroll
      for (int i = 0; i < 4; ++i) {
        const int row = wm + i * 16 + (lane & 15);
        a[i] = *reinterpret_cast<const bf16x8*>(
            &As[row * BK + (klane ^ ((row & 7) << 3))]);
      }
#pragma unroll
      for (int j = 0; j < 4; ++j) {
        const int row = wn + j * 16 + (lane & 15);
        b[j] = *reinterpret_cast<const bf16x8*>(
            &Bs[row * BK + (klane ^ ((row & 7) << 3))]);
      }
#pragma unroll
      for (int i = 0; i < 4; ++i)
#pragma unroll
        for (int j = 0; j < 4; ++j)
          acc[i][j] = __builtin_amdgcn_mfma_f32_16x16x32_bf16(a[i], b[j], acc[i][j], 0, 0, 0);
    }
  }

  // ---- Epilogue (C/D map m89/m91): col=lane&15, row=(lane>>4)*4+r
  const int colbase = n0 + wn + (lane & 15);
  const int rowbase = m0 + wm + ((lane >> 4) << 2);
#pragma unroll
  for (int j = 0; j < 4; ++j) {
    const int col = colbase + j * 16;
    const float bv = Bias[col];
#pragma unroll
    for (int i = 0; i < 4; ++i) {
      const int row = rowbase + i * 16;
#pragma unroll
      for (int r = 0; r < 4; ++r)
        Out[(size_t)(row + r) * N + col] = acc[i][j][r] + bv;
    }
  }
}

extern "C" void kernel_launch(void* const* d_in, const int* in_sizes, int n_in,
                              void* d_out, int out_size, void* d_ws, size_t ws_size,
                              hipStream_t stream) {
  const float* x    = (const float*)d_in[0];
  const int*   q    = (const int*)d_in[1];
  const float* s    = (const float*)d_in[2];
  const float* z    = (const float*)d_in[3];
  const float* bias = (const float*)d_in[4];
  float*       out  = (float*)d_out;

  const int N  = in_sizes[4];              // 11008
  const int K  = in_sizes[1] / N;          // 4096
  const int M  = in_sizes[0] / K;          // 2048
  const int G  = in_sizes[2] / N;          // 32
  const int GS = K / G;                    // 128

  unsigned short* Wb = (unsigned short*)d_ws;            // N*K bf16 = 90MB
  unsigned short* Xb = Wb + (size_t)N * K;               // M*K bf16 = 17MB

  const int wblocks = (int)(((size_t)N * K / 8 + 255) / 256);   // 22016
  wdequant_kernel<<<wblocks, 256, 0, stream>>>(q, s, z, Wb, N, K, GS);
  const int xblocks = (M * K / 8 + 255) / 256;                  // 4096
  xconv_kernel<<<xblocks, 256, 0, stream>>>(x, Xb, M, K);

  const int grid = (M / BM) * (N / BN);                         // 1376 = 8*172
  gemm_kernel<<<grid, NTHREADS, 0, stream>>>(Xb, Wb, bias, out, M, N, K);
}